// Round 1
// 72.874 us; speedup vs baseline: 1.0085x; 1.0085x over previous
//
#include <hip/hip_runtime.h>

#define S_DIM 363      // GRID = ceil(sqrt(2)*256)
#define S_P   368      // per-angle row stride in 8-B entries (16-B multiple)
#define A_DIM 180      // N_THETA
#define OUT_W 256
#define F_PI 3.14159265358979323846f

typedef float    f4 __attribute__((ext_vector_type(4)));
typedef _Float16 h4 __attribute__((ext_vector_type(4)));
union HU { uint2 u; h4 h; };

// Filtered sinogram, PLAIN (de-duplicated) fp16 layout: g_sino[a*S_P + 1 + t]
// holds y_a[t] for all 4 batches (8 B, batch-interleaved). Guard entries
// g[a][0] = 0 (y[-1]) and g[a][364] = 0 (y[363]) reproduce the reference's
// clip+zero-weight edge semantics exactly. Backprojection reads the two
// interp taps as TWO ADJACENT dwordx2 loads (k1, k1+1) - same 16 B of taps
// as the old paired layout, but each y value is fetched through L1 ONCE
// instead of twice (footprint 1.06 MB -> 530 KB, ~half the L1 lines/wave).
// Fully rewritten every call before kernel 2 reads it.
__device__ uint2 g_sino[A_DIM * S_P];

// ---------------------------------------------------------------------------
// Kernel 1: ramp filter as direct spatial convolution (exact rewrite of the
// reference FFT path: circular conv, g[0]=0.5, g[d]=-2/(pi*d)^2 for odd d,
// 0 for even d; |t-s| <= 362 < 512 so weight depends only on |t-s|).
// One block per angle (384 thr): column staged once, parity pruning halves
// the taps, all 4 batches per thread via f4 LDS reads (wave touches 2 LDS
// addresses/iter -> broadcast, conflict-free). Output now stored DIRECTLY
// as h4 rows (the old ys[] round-trip + pair-assembly pass is gone).
// ---------------------------------------------------------------------------
__global__ __launch_bounds__(384) void iradon_filter_kernel(
        const float* __restrict__ x) {
    __shared__ f4    xs4[S_DIM];   // per-s, batch-interleaved f32
    __shared__ float wt[182];      // wt[k] = -2/(pi*(2k+1))^2

    const int a   = blockIdx.x;    // 0..179
    const int tid = threadIdx.x;

    if (tid < S_DIM) {
        f4 v;
        v.x = x[(0 * S_DIM + tid) * A_DIM + a];
        v.y = x[(1 * S_DIM + tid) * A_DIM + a];
        v.z = x[(2 * S_DIM + tid) * A_DIM + a];
        v.w = x[(3 * S_DIM + tid) * A_DIM + a];
        xs4[tid] = v;
    }
    if (tid < 182) {
        float d = (float)(2 * tid + 1);
        wt[tid] = -2.0f / (F_PI * F_PI * d * d);
    }
    __syncthreads();

    if (tid < S_DIM) {
        f4 acc = 0.5f * xs4[tid];          // d == 0 term (exact f32 input)
        const int s0 = 1 - (tid & 1);      // opposite parity of t
        #pragma unroll 4
        for (int s = s0; s < S_DIM; s += 2) {
            int d = s - tid; d = (d < 0) ? -d : d;
            float w = wt[d >> 1];
            acc += w * xs4[s];             // 2x v_pk_fma_f32
        }
        HU r; r.h = __builtin_convertvector(acc, h4);
        g_sino[a * S_P + 1 + tid] = r.u;   // y[t] at entry 1+t
    }
    if (tid == 363) { HU z; z.u.x = 0u; z.u.y = 0u; g_sino[a * S_P + 0]   = z.u; }
    if (tid == 364) { HU z; z.u.x = 0u; z.u.y = 0u; g_sino[a * S_P + 364] = z.u; }
}

// ---------------------------------------------------------------------------
// Kernel 2: backprojection. pos = (j-128)*cos - (i-128)*sin + 181.
// f = floor(pos), k1 = (int)f + 1 in [0,363]: lo = g[a][k1] = y[f] (or the
// zero guard), hi = g[a][k1+1] = y[f+1] (or guard) -- two adjacent 8-B loads,
// the second folds to an immediate offset. f32 accumulation via
// (float)half * f32 FMAs (v_fma_mix_f32).
// Wave mapping changed to 64(j) x 1(i): one output row per block, so each
// wave-load spans ~64|c| contiguous entries x 8 B -> fewer distinct L1 lines
// than the old 32x2 mapping, and nii is wave-uniform.
// Block = 256 thr = 64(j) x 4 angle-quarters. Grid = 4 x 256.
// ---------------------------------------------------------------------------
__global__ __launch_bounds__(256) void iradon_backproject_kernel(
        float* __restrict__ out) {
    __shared__ float cs[A_DIM];
    __shared__ float sn[A_DIM];
    __shared__ f4 red[256];

    const int tid = threadIdx.x;
    if (tid < A_DIM) {
        float th = (float)tid * (F_PI / 180.0f);
        cs[tid] = cosf(th);
        sn[tid] = sinf(th);
    }
    __syncthreads();

    const int px = tid & 63;
    const int q  = tid >> 6;           // wave index = angle quarter (uniform/wave)
    const int j  = blockIdx.x * 64 + px;
    const int i  = blockIdx.y;

    const float jj  = (float)(j - 128);
    const float nii = (float)(128 - i);    // -(i-128), wave-uniform

    f4 acc = (f4)0.0f;
    const int a0 = q * 45;
    #pragma unroll 3
    for (int m = 0; m < 45; ++m) {
        const int a = a0 + m;
        const float c = cs[a];             // broadcast LDS reads
        const float s = sn[a];
        float pos = fmaf(jj, c, fmaf(nii, s, 181.0f));
        float f   = floorf(pos);
        int   k1  = (int)f + 1;            // in [0, 363]
        float w1  = pos - f;
        float w0  = 1.0f - w1;
        const uint2* __restrict__ row = g_sino + a * S_P;
        HU lo, hi;
        lo.u = row[k1];                    // y[k]   x4 batches (8 B)
        hi.u = row[k1 + 1];                // y[k+1] x4 batches (offset:8)
        acc.x = fmaf((float)lo.h.x, w0, fmaf((float)hi.h.x, w1, acc.x));
        acc.y = fmaf((float)lo.h.y, w0, fmaf((float)hi.h.y, w1, acc.y));
        acc.z = fmaf((float)lo.h.z, w0, fmaf((float)hi.h.z, w1, acc.z));
        acc.w = fmaf((float)lo.h.w, w0, fmaf((float)hi.h.w, w1, acc.w));
    }

    red[tid] = acc;
    __syncthreads();

    if (tid < 64) {
        f4 r = red[tid] + red[tid + 64] + red[tid + 128] + red[tid + 192];
        r *= (F_PI / 360.0f);
        const int jo   = blockIdx.x * 64 + tid;
        const size_t p = (size_t)blockIdx.y * OUT_W + jo;
        out[p]              = r.x;
        out[p +     65536]  = r.y;
        out[p + 2 * 65536]  = r.z;
        out[p + 3 * 65536]  = r.w;
    }
}

extern "C" void kernel_launch(void* const* d_in, const int* in_sizes, int n_in,
                              void* d_out, int out_size, void* d_ws, size_t ws_size,
                              hipStream_t stream) {
    const float* x = (const float*)d_in[0];
    float* out = (float*)d_out;

    iradon_filter_kernel<<<dim3(A_DIM), 384, 0, stream>>>(x);
    iradon_backproject_kernel<<<dim3(4, OUT_W), 256, 0, stream>>>(out);
}